// Round 2
// baseline (991.545 us; speedup 1.0000x reference)
//
#include <hip/hip_runtime.h>

typedef unsigned short u16;
typedef unsigned int u32;

#define NB   128
#define NT   1024
#define NENC 768
#define NH   256
#define NMELS 400

// ---- workspace layout (float offsets); total ~286K floats = 1.15 MB ----
constexpr int OFF_FLAG  = 0;                      // int mode at ws[0]
constexpr int OFF_HATTN = 16;                     // 128*256 fp32 h_att_n
constexpr int OFF_G     = OFF_HATTN + NB*NH;      // 128*168 dynamic filters
constexpr int OFF_ALPHA = OFF_G + NB*168;         // 128*1024 fp32 alpha
constexpr int OFF_DCS   = OFF_ALPHA + NB*NT;      // 128*768 fp32 dcs accumulator
constexpr int OFF_UT    = OFF_DCS + NB*NENC;      // 128*16 [Uw|Tw]
constexpr int OFF_TBF   = OFF_UT + 2048;          // 128
constexpr int OFF_VWF   = OFF_TBF + 128;          // 128
constexpr int OFF_FKF   = OFF_VWF + 128;          // 168
constexpr int OFF_PF    = OFF_FKF + 168;          // 11

// ---- output layout (elements, concatenated in return order) ----
constexpr int OUT_MEL   = 0;                      // 128*400
constexpr int OUT_ALPHA = OUT_MEL + NB*NMELS;     // 128*1024
constexpr int OUT_DCS   = OUT_ALPHA + NB*NT;      // 128*768
constexpr int OUT_HATT  = OUT_DCS + NB*NENC;      // 128*256
constexpr int OUT_H1    = OUT_HATT + NB*NH;       // 128*256
constexpr int OUT_H2    = OUT_H1 + NB*NH;         // 128*256

__device__ __forceinline__ float bfd(u16 u){ u32 x = ((u32)u) << 16; return __builtin_bit_cast(float, x); }
__device__ __forceinline__ float bflo(u32 u){ return __builtin_bit_cast(float, u << 16); }
__device__ __forceinline__ float bfhi(u32 u){ return __builtin_bit_cast(float, u & 0xffff0000u); }
__device__ __forceinline__ u16 f2bf(float f){
  u32 x = __builtin_bit_cast(u32, f);
  u32 r = x + 0x7fffu + ((x >> 16) & 1u);   // RNE
  return (u16)(r >> 16);
}
__device__ __forceinline__ float sigm(float x){ return 1.f / (1.f + __expf(-x)); }
__device__ __forceinline__ float tanh_(float x){
  float e = __expf(2.f * x);
  return 1.f - 2.f / (e + 1.f);
}

// M=1: bf16 storage; M=0: fp32 storage
template<int M> __device__ __forceinline__ float ld1(const void* p, size_t i){
  if constexpr (M) return bfd(((const u16*)p)[i]);
  else return ((const float*)p)[i];
}
// elements (2*k2, 2*k2+1)
template<int M> __device__ __forceinline__ float2 ldpair(const void* p, size_t k2){
  if constexpr (M){ u32 u = ((const u32*)p)[k2]; float2 r; r.x = bflo(u); r.y = bfhi(u); return r; }
  else return ((const float2*)p)[k2];
}
template<int M> __device__ __forceinline__ void st1(void* p, size_t i, float v){
  if constexpr (M) ((u16*)p)[i] = f2bf(v);
  else ((float*)p)[i] = v;
}

// GRU for hidden unit j (gate order r,z,n); xs length K, hs length 256
template<int M, int K>
__device__ __forceinline__ float gru_unit(const float* xs, const float* hs,
    const void* wih, const void* whh, const void* bih, const void* bhh, int j){
  float ir = ld1<M>(bih, j), iz = ld1<M>(bih, 256 + j), in_ = ld1<M>(bih, 512 + j);
  {
    size_t r0 = (size_t)j * (K / 2), z0 = (size_t)(256 + j) * (K / 2), n0 = (size_t)(512 + j) * (K / 2);
    #pragma unroll 4
    for (int k2 = 0; k2 < K / 2; k2++){
      float x0 = xs[2 * k2], x1 = xs[2 * k2 + 1];
      float2 wr = ldpair<M>(wih, r0 + k2);
      float2 wz = ldpair<M>(wih, z0 + k2);
      float2 wn = ldpair<M>(wih, n0 + k2);
      ir = fmaf(x0, wr.x, fmaf(x1, wr.y, ir));
      iz = fmaf(x0, wz.x, fmaf(x1, wz.y, iz));
      in_ = fmaf(x0, wn.x, fmaf(x1, wn.y, in_));
    }
  }
  float hr = ld1<M>(bhh, j), hz = ld1<M>(bhh, 256 + j), hn = ld1<M>(bhh, 512 + j);
  {
    size_t r0 = (size_t)j * 128, z0 = (size_t)(256 + j) * 128, n0 = (size_t)(512 + j) * 128;
    #pragma unroll 4
    for (int k2 = 0; k2 < 128; k2++){
      float h0 = hs[2 * k2], h1 = hs[2 * k2 + 1];
      float2 wr = ldpair<M>(whh, r0 + k2);
      float2 wz = ldpair<M>(whh, z0 + k2);
      float2 wn = ldpair<M>(whh, n0 + k2);
      hr = fmaf(h0, wr.x, fmaf(h1, wr.y, hr));
      hz = fmaf(h0, wz.x, fmaf(h1, wz.y, hz));
      hn = fmaf(h0, wn.x, fmaf(h1, wn.y, hn));
    }
  }
  float r = sigm(ir + hr), z = sigm(iz + hz);
  float n = tanh_(in_ + r * hn);
  return (1.f - z) * n + z * hs[j];
}

// ---- kernel 0: dtype detection + unpack tiny DCA weights to fp32 ----
template<int M>
__device__ __forceinline__ void prep_body(const void* Uw, const void* Tw, const void* Tb,
    const void* vw, const void* Fk, const void* P, float* ws, int j){
  for (int i = j; i < 2048; i += 256){
    int m = i >> 4, c = i & 15;
    ws[OFF_UT + i] = (c < 8) ? ld1<M>(Uw, m * 8 + c) : ld1<M>(Tw, m * 8 + (c - 8));
  }
  if (j < 128){ ws[OFF_TBF + j] = ld1<M>(Tb, j); ws[OFF_VWF + j] = ld1<M>(vw, j); }
  if (j < 168) ws[OFF_FKF + j] = ld1<M>(Fk, j);
  if (j < 11)  ws[OFF_PF + j]  = ld1<M>(P, j);
}

__global__ void prep_kernel(const void* enc, const void* Uw, const void* Tw, const void* Tb,
                            const void* vw, const void* Fk, const void* P, float* ws){
  int j = threadIdx.x;  // 256
  __shared__ int cnt;
  if (j == 0) cnt = 0;
  __syncthreads();
  // If storage is bf16, the low u16 of each u32 word is a genuine small bf16
  // (exponent <= ~0x85 for N(0,1) data). If storage is fp32, low 16 bits are
  // ~uniform -> ~25% of words have bf16-exponent >= 0xC0.
  int c = 0;
  const u32* ep = (const u32*)enc;
  for (int i = j; i < 1024; i += 256){
    u32 w = ep[i] & 0xffffu;
    int ex = (int)((w >> 7) & 0xff);
    if (ex >= 0xC0) c++;
  }
  if (c) atomicAdd(&cnt, c);
  __syncthreads();
  int mode = (cnt > 8) ? 0 : 1;   // 1 = bf16, 0 = fp32
  if (j == 0) ((int*)ws)[OFF_FLAG] = mode;
  if (mode) prep_body<1>(Uw, Tw, Tb, vw, Fk, P, ws, j);
  else      prep_body<0>(Uw, Tw, Tb, vw, Fk, P, ws, j);
}

// ---- kernel 1: prenet + attention GRU + dynamic filter G (one block per b) ----
template<int M>
__device__ __forceinline__ void head_body(const void* prev_frame, const void* dcs_state,
    const void* h_att, const void* pre_w1, const void* pre_b1, const void* pre_w2, const void* pre_b2,
    const void* att_wih, const void* att_whh, const void* att_bih, const void* att_bhh,
    const void* Ww, const void* Wb, const void* Vw,
    float* ws, void* out, float* sm){
  float* pf = sm;            // 400
  float* o1 = sm + 400;      // 256
  float* xc = sm + 656;      // 896
  float* hv = sm + 1552;     // 256
  float* hn = sm + 1808;     // 256
  float* t1 = sm + 2064;     // 128
  int b = blockIdx.x, j = threadIdx.x;
  for (int k = j; k < NMELS; k += 256) pf[k] = ld1<M>(prev_frame, (size_t)b * NMELS + k);
  for (int k = j; k < 768; k += 256)   xc[k] = ld1<M>(dcs_state, (size_t)b * 768 + k);
  hv[j] = ld1<M>(h_att, (size_t)b * 256 + j);
  __syncthreads();
  // prenet layer 1: relu(pf @ pre_w1^T + b1), K=400
  {
    float a = ld1<M>(pre_b1, j);
    size_t w0 = (size_t)j * 200;
    #pragma unroll 4
    for (int k2 = 0; k2 < 200; k2++){
      float2 w = ldpair<M>(pre_w1, w0 + k2);
      a = fmaf(pf[2 * k2], w.x, fmaf(pf[2 * k2 + 1], w.y, a));
    }
    o1[j] = fmaxf(a, 0.f);
  }
  __syncthreads();
  // prenet layer 2: relu(o1 @ pre_w2^T + b2), K=256 -> xc[768..896)
  if (j < 128){
    float a = ld1<M>(pre_b2, j);
    size_t w0 = (size_t)j * 128;
    #pragma unroll 4
    for (int k2 = 0; k2 < 128; k2++){
      float2 w = ldpair<M>(pre_w2, w0 + k2);
      a = fmaf(o1[2 * k2], w.x, fmaf(o1[2 * k2 + 1], w.y, a));
    }
    xc[768 + j] = fmaxf(a, 0.f);
  }
  __syncthreads();
  // attention GRU (K=896)
  float hnew = gru_unit<M, 896>(xc, hv, att_wih, att_whh, att_bih, att_bhh, j);
  hn[j] = hnew;
  ws[OFF_HATTN + b * 256 + j] = hnew;
  st1<M>(out, OUT_HATT + (size_t)b * 256 + j, hnew);
  __syncthreads();
  // t1 = tanh(h_att_n @ Ww^T + Wb), K=256
  if (j < 128){
    float a = ld1<M>(Wb, j);
    size_t w0 = (size_t)j * 128;
    #pragma unroll 4
    for (int k2 = 0; k2 < 128; k2++){
      float2 w = ldpair<M>(Ww, w0 + k2);
      a = fmaf(hn[2 * k2], w.x, fmaf(hn[2 * k2 + 1], w.y, a));
    }
    t1[j] = tanh_(a);
  }
  __syncthreads();
  // G = t1 @ Vw^T, K=128, 168 outputs
  if (j < 168){
    float a = 0.f;
    size_t w0 = (size_t)j * 64;
    #pragma unroll 4
    for (int k2 = 0; k2 < 64; k2++){
      float2 w = ldpair<M>(Vw, w0 + k2);
      a = fmaf(t1[2 * k2], w.x, fmaf(t1[2 * k2 + 1], w.y, a));
    }
    ws[OFF_G + b * 168 + j] = a;
  }
}

__global__ __launch_bounds__(256)
void head_kernel(const void* prev_frame, const void* dcs_state, const void* h_att,
    const void* pre_w1, const void* pre_b1, const void* pre_w2, const void* pre_b2,
    const void* att_wih, const void* att_whh, const void* att_bih, const void* att_bhh,
    const void* Ww, const void* Wb, const void* Vw, float* ws, void* out){
  __shared__ float sm[2192];
  if (((const int*)ws)[OFF_FLAG])
    head_body<1>(prev_frame, dcs_state, h_att, pre_w1, pre_b1, pre_w2, pre_b2,
                 att_wih, att_whh, att_bih, att_bhh, Ww, Wb, Vw, ws, out, sm);
  else
    head_body<0>(prev_frame, dcs_state, h_att, pre_w1, pre_b1, pre_w2, pre_b2,
                 att_wih, att_whh, att_bih, att_bhh, Ww, Wb, Vw, ws, out, sm);
}

// ---- kernel 2: DCA energies + softmax (one block per b); also zeroes dcs acc ----
template<int M>
__device__ __forceinline__ void dca_body(const void* prev_att, float* ws, void* out, float* sm){
  float* apad = sm;            // 1044
  float* red  = sm + 1044;     // 16
  float* bc   = sm + 1060;     // 2
  int b = blockIdx.x, t = threadIdx.x;
  // zero dcs accumulator row b (consumed by dcs_kernel's atomicAdd)
  if (t < NENC) ws[OFF_DCS + b * NENC + t] = 0.f;
  if (t < 10){ apad[t] = 0.f; apad[NT + 10 + t] = 0.f; }
  apad[10 + t] = ld1<M>(prev_att, (size_t)b * NT + t);
  __syncthreads();
  float ap[21];
  #pragma unroll
  for (int k = 0; k < 21; k++) ap[k] = apad[t + k];
  // prior
  const float* Pw = ws + OFF_PF;
  float pv = 0.f;
  #pragma unroll
  for (int jj = 0; jj < 11; jj++) pv = fmaf(Pw[jj], ap[jj], pv);
  pv = __logf(fmaxf(pv, 1e-6f));
  // static conv f and dynamic conv g, 8 ch x 21 taps
  const float* Fw = ws + OFF_FKF;
  const float* Gw = ws + OFF_G + b * 168;
  float fg[16];
  #pragma unroll
  for (int c = 0; c < 8; c++){
    float fa = 0.f, ga = 0.f;
    #pragma unroll
    for (int k = 0; k < 21; k++){
      fa = fmaf(Fw[c * 21 + k], ap[k], fa);
      ga = fmaf(Gw[c * 21 + k], ap[k], ga);
    }
    fg[c] = fa; fg[8 + c] = ga;
  }
  // e = vw . tanh(UT @ [f;g] + Tb) + p
  const float* UT  = ws + OFF_UT;
  const float* Tbf = ws + OFF_TBF;
  const float* vwf = ws + OFF_VWF;
  float e = pv;
  #pragma unroll 4
  for (int m = 0; m < 128; m++){
    float h = Tbf[m];
    #pragma unroll
    for (int c = 0; c < 16; c++) h = fmaf(UT[m * 16 + c], fg[c], h);
    e = fmaf(vwf[m], tanh_(h), e);
  }
  // softmax over T=1024
  float mx = e;
  #pragma unroll
  for (int off = 1; off < 64; off <<= 1) mx = fmaxf(mx, __shfl_xor(mx, off));
  if ((t & 63) == 0) red[t >> 6] = mx;
  __syncthreads();
  if (t == 0){ float m2 = red[0]; for (int i = 1; i < 16; i++) m2 = fmaxf(m2, red[i]); bc[0] = m2; }
  __syncthreads();
  float ex = __expf(e - bc[0]);
  float smv = ex;
  #pragma unroll
  for (int off = 1; off < 64; off <<= 1) smv += __shfl_xor(smv, off);
  if ((t & 63) == 0) red[t >> 6] = smv;
  __syncthreads();
  if (t == 0){ float s2 = 0.f; for (int i = 0; i < 16; i++) s2 += red[i]; bc[1] = s2; }
  __syncthreads();
  float al = ex / bc[1];
  ws[OFF_ALPHA + b * NT + t] = al;
  st1<M>(out, OUT_ALPHA + (size_t)b * NT + t, al);
}

__global__ __launch_bounds__(1024)
void dca_e_kernel(const void* prev_att, float* ws, void* out){
  __shared__ float sm[1062];
  if (((const int*)ws)[OFF_FLAG]) dca_body<1>(prev_att, ws, out, sm);
  else                            dca_body<0>(prev_att, ws, out, sm);
}

// ---- kernel 3: dcs (HBM-bound): grid (8 chunks, 128 b), 192 thr x 4 cols, atomicAdd ----
template<int M>
__device__ __forceinline__ void dcs_body(const void* enc, float* ws, float* sA){
  int ch = blockIdx.x, b = blockIdx.y, j = threadIdx.x;
  int t0 = ch * 128;
  if (j < 128) sA[j] = ws[OFF_ALPHA + b * NT + t0 + j];
  __syncthreads();
  float a0 = 0.f, a1 = 0.f, a2 = 0.f, a3 = 0.f;
  size_t wbase = ((size_t)(b * NT + t0) * NENC) / 2 + 2 * j;   // pair index
  #pragma unroll 4
  for (int tl = 0; tl < 128; tl++){
    float a = sA[tl];
    float2 p0 = ldpair<M>(enc, wbase + (size_t)tl * (NENC / 2));
    float2 p1 = ldpair<M>(enc, wbase + (size_t)tl * (NENC / 2) + 1);
    a0 = fmaf(a, p0.x, a0);
    a1 = fmaf(a, p0.y, a1);
    a2 = fmaf(a, p1.x, a2);
    a3 = fmaf(a, p1.y, a3);
  }
  float* o = ws + OFF_DCS + (size_t)b * NENC + 4 * j;
  atomicAdd(o + 0, a0);
  atomicAdd(o + 1, a1);
  atomicAdd(o + 2, a2);
  atomicAdd(o + 3, a3);
}

__global__ __launch_bounds__(192)
void dcs_kernel(const void* enc, float* ws){
  __shared__ float sA[128];
  if (((const int*)ws)[OFF_FLAG]) dcs_body<1>(enc, ws, sA);
  else                            dcs_body<0>(enc, ws, sA);
}

// ---- kernel 4: dcs out + lin + GRU1 + GRU2 + proj (one block per b) ----
template<int M>
__device__ __forceinline__ void tail_body(float* ws,
    const void* lin_w, const void* lin_b,
    const void* r1_wih, const void* r1_whh, const void* r1_bih, const void* r1_bhh,
    const void* r2_wih, const void* r2_whh, const void* r2_bih, const void* r2_bhh,
    const void* proj_w, const void* proj_b,
    const void* h1_in, const void* h2_in, void* out, float* sm){
  float* xc  = sm;            // 1024
  float* sx  = sm + 1024;     // 256
  float* sx2 = sm + 1280;     // 256
  float* sx3 = sm + 1536;     // 256
  float* h1s = sm + 1792;     // 256
  float* h2s = sm + 2048;     // 256
  int b = blockIdx.x, j = threadIdx.x;
  for (int k = j; k < NENC; k += 256){
    float s = ws[OFF_DCS + (size_t)b * NENC + k];
    xc[k] = s;
    st1<M>(out, OUT_DCS + (size_t)b * NENC + k, s);
  }
  xc[768 + j] = ws[OFF_HATTN + b * 256 + j];
  h1s[j] = ld1<M>(h1_in, (size_t)b * 256 + j);
  h2s[j] = ld1<M>(h2_in, (size_t)b * 256 + j);
  __syncthreads();
  // lin: x = [dcs, h_att_n] @ lin_w^T + lin_b, K=1024
  {
    float a = ld1<M>(lin_b, j);
    size_t w0 = (size_t)j * 512;
    #pragma unroll 4
    for (int k2 = 0; k2 < 512; k2++){
      float2 w = ldpair<M>(lin_w, w0 + k2);
      a = fmaf(xc[2 * k2], w.x, fmaf(xc[2 * k2 + 1], w.y, a));
    }
    sx[j] = a;
  }
  __syncthreads();
  float h1n = gru_unit<M, 256>(sx, h1s, r1_wih, r1_whh, r1_bih, r1_bhh, j);
  st1<M>(out, OUT_H1 + (size_t)b * 256 + j, h1n);
  sx2[j] = sx[j] + h1n;
  __syncthreads();
  float h2n = gru_unit<M, 256>(sx2, h2s, r2_wih, r2_whh, r2_bih, r2_bhh, j);
  st1<M>(out, OUT_H2 + (size_t)b * 256 + j, h2n);
  sx3[j] = sx2[j] + h2n;
  __syncthreads();
  for (int o = j; o < NMELS; o += 256){
    float a = ld1<M>(proj_b, o);
    size_t w0 = (size_t)o * 128;
    #pragma unroll 4
    for (int k2 = 0; k2 < 128; k2++){
      float2 w = ldpair<M>(proj_w, w0 + k2);
      a = fmaf(sx3[2 * k2], w.x, fmaf(sx3[2 * k2 + 1], w.y, a));
    }
    st1<M>(out, OUT_MEL + (size_t)b * NMELS + o, a);
  }
}

__global__ __launch_bounds__(256)
void tail_kernel(float* ws,
    const void* lin_w, const void* lin_b,
    const void* r1_wih, const void* r1_whh, const void* r1_bih, const void* r1_bhh,
    const void* r2_wih, const void* r2_whh, const void* r2_bih, const void* r2_bhh,
    const void* proj_w, const void* proj_b,
    const void* h1_in, const void* h2_in, void* out){
  __shared__ float sm[2304];
  if (((const int*)ws)[OFF_FLAG])
    tail_body<1>(ws, lin_w, lin_b, r1_wih, r1_whh, r1_bih, r1_bhh,
                 r2_wih, r2_whh, r2_bih, r2_bhh, proj_w, proj_b, h1_in, h2_in, out, sm);
  else
    tail_body<0>(ws, lin_w, lin_b, r1_wih, r1_whh, r1_bih, r1_bhh,
                 r2_wih, r2_whh, r2_bih, r2_bhh, proj_w, proj_b, h1_in, h2_in, out, sm);
}

extern "C" void kernel_launch(void* const* d_in, const int* in_sizes, int n_in,
                              void* d_out, int out_size, void* d_ws, size_t ws_size,
                              hipStream_t stream){
  (void)in_sizes; (void)n_in; (void)out_size; (void)ws_size;
  const void* enc       = d_in[0];
  const void* prev_frame= d_in[1];
  const void* prev_att  = d_in[2];
  const void* dcs_state = d_in[3];
  const void* h_att     = d_in[4];
  const void* h1        = d_in[5];
  const void* h2        = d_in[6];
  const void* pre_w1    = d_in[7];
  const void* pre_b1    = d_in[8];
  const void* pre_w2    = d_in[9];
  const void* pre_b2    = d_in[10];
  const void* dca_Ww    = d_in[11];
  const void* dca_Wb    = d_in[12];
  const void* dca_Vw    = d_in[13];
  const void* dca_Fk    = d_in[14];
  const void* dca_Uw    = d_in[15];
  const void* dca_Tw    = d_in[16];
  const void* dca_Tb    = d_in[17];
  const void* dca_vw    = d_in[18];
  const void* att_wih   = d_in[19];
  const void* att_whh   = d_in[20];
  const void* att_bih   = d_in[21];
  const void* att_bhh   = d_in[22];
  const void* lin_w     = d_in[23];
  const void* lin_b     = d_in[24];
  const void* r1_wih    = d_in[25];
  const void* r1_whh    = d_in[26];
  const void* r1_bih    = d_in[27];
  const void* r1_bhh    = d_in[28];
  const void* r2_wih    = d_in[29];
  const void* r2_whh    = d_in[30];
  const void* r2_bih    = d_in[31];
  const void* r2_bhh    = d_in[32];
  const void* proj_w    = d_in[33];
  const void* proj_b    = d_in[34];
  const void* P         = d_in[35];
  float* ws = (float*)d_ws;
  void* out = d_out;

  prep_kernel<<<1, 256, 0, stream>>>(enc, dca_Uw, dca_Tw, dca_Tb, dca_vw, dca_Fk, P, ws);
  head_kernel<<<NB, 256, 0, stream>>>(prev_frame, dcs_state, h_att,
      pre_w1, pre_b1, pre_w2, pre_b2,
      att_wih, att_whh, att_bih, att_bhh,
      dca_Ww, dca_Wb, dca_Vw, ws, out);
  dca_e_kernel<<<NB, 1024, 0, stream>>>(prev_att, ws, out);
  dcs_kernel<<<dim3(8, NB), 192, 0, stream>>>(enc, ws);
  tail_kernel<<<NB, 256, 0, stream>>>(ws, lin_w, lin_b,
      r1_wih, r1_whh, r1_bih, r1_bhh,
      r2_wih, r2_whh, r2_bih, r2_bhh,
      proj_w, proj_b, h1, h2, out);
}